// Round 5
// baseline (122.957 us; speedup 1.0000x reference)
//
#include <hip/hip_runtime.h>

#define CUT0 20000
#define CUT1 60000
#define D    1024
#define D1   256
#define D2   64
#define NTOK 32768

typedef __bf16  bf16x8 __attribute__((ext_vector_type(8)));
typedef float   f32x4  __attribute__((ext_vector_type(4)));

// ws layout:
//   int      cnt[64]                          (n0, n1, n2, pad)
//   unsigned list0[NTOK], list1[NTOK], list2[NTOK]   packed (tok<<17)|local_idx
//   __bf16   w1b[D*D1]   (same [d][k] layout as w1 — rows are MFMA A-operand)
//   __bf16   w2b[D*D2]

__global__ void k_init(int* cnt) {
    if (threadIdx.x < 3) cnt[threadIdx.x] = 0;
}

__global__ __launch_bounds__(256) void k_classify(
        const int* __restrict__ ids,
        const float* __restrict__ w1,
        const float* __restrict__ w2,
        int* cnt, unsigned* list0, unsigned* list1, unsigned* list2,
        __bf16* __restrict__ w1b, __bf16* __restrict__ w2b) {
    int bid = blockIdx.x, tid = threadIdx.x;
    if (bid < NTOK / 256) {
        unsigned t = bid * 256 + tid;
        int id = ids[t];
        int lane = tid & 63;
        unsigned long long lanebit = 1ull << lane;
        int c = (id < CUT0) ? 0 : (id < CUT1 ? 1 : 2);
        {
            unsigned long long m = __ballot(c == 0);
            if (m) {
                int base = 0;
                if (lane == 0) base = atomicAdd(cnt + 0, __popcll(m));
                base = __shfl(base, 0);
                if (c == 0) list0[base + __popcll(m & (lanebit - 1))] = (t << 17) | (unsigned)id;
            }
        }
        {
            unsigned long long m = __ballot(c == 1);
            if (m) {
                int base = 0;
                if (lane == 0) base = atomicAdd(cnt + 1, __popcll(m));
                base = __shfl(base, 0);
                if (c == 1) list1[base + __popcll(m & (lanebit - 1))] = (t << 17) | (unsigned)(id - CUT0);
            }
        }
        {
            unsigned long long m = __ballot(c == 2);
            if (m) {
                int base = 0;
                if (lane == 0) base = atomicAdd(cnt + 2, __popcll(m));
                base = __shfl(base, 0);
                if (c == 2) list2[base + __popcll(m & (lanebit - 1))] = (t << 17) | (unsigned)(id - CUT1);
            }
        }
    } else {
        // cast w1 (1024x256) then w2 (1024x64) to bf16, same layout
        int i = (bid - NTOK / 256) * 256 + tid;
        if (i < D1 * D) {
            w1b[i] = (__bf16)w1[i];
        } else {
            int j = i - D1 * D;          // j < D2*D by grid sizing
            w2b[j] = (__bf16)w2[j];
        }
    }
}

__global__ __launch_bounds__(256) void k_copy0(
        const float* __restrict__ emb0,
        float* __restrict__ out,
        const int* __restrict__ cnt,
        const unsigned* __restrict__ list0) {
    int n0 = cnt[0];
    for (int r = blockIdx.x; r < n0; r += gridDim.x) {
        unsigned p = list0[r];
        unsigned tok = p >> 17, id = p & 0x1FFFFu;
        const float4* src = (const float4*)(emb0 + (size_t)id * D);
        float4* dst = (float4*)(out + (size_t)tok * D);
        dst[threadIdx.x] = src[threadIdx.x];
    }
}

// Swapped-operand MFMA slice: D-tile = W(16d x K) * E(K x 16tok).
// A-frag: lane holds w row d = dbase+t*16+(lane&15), k = (lane>>4)*8+j
// B-frag: lane holds emb col tok(lane&15),           k = (lane>>4)*8+j
// C/D:    col = lane&15 (token), row = (lane>>4)*4+r (d)  -> float4 store/lane
template<int K, int KS>
__device__ __forceinline__ void gemm_slice(
        const float* __restrict__ emb, const __bf16* __restrict__ wb,
        const float* __restrict__ bias, float* __restrict__ out,
        const unsigned* __restrict__ list, int n, int base, int dbase, int lane) {
    int col = lane & 15;      // token slot == D col; also A d-row local idx
    int kg  = lane >> 4;      // k-group
    int nt  = min(16, n - base);
    int li  = base + col;
    unsigned p = list[li < n ? li : n - 1];
    unsigned lidx = p & 0x1FFFFu;
    unsigned tok  = p >> 17;

    f32x4 acc[16];
#pragma unroll
    for (int t = 0; t < 16; t++) acc[t] = (f32x4){0.f, 0.f, 0.f, 0.f};

    const float* bp = emb + (size_t)lidx * K + kg * 8;

#pragma unroll
    for (int ks = 0; ks < KS; ks++) {
        float4 x = *(const float4*)(bp);
        float4 y = *(const float4*)(bp + 4);
        bf16x8 b;
        b[0] = (__bf16)x.x; b[1] = (__bf16)x.y; b[2] = (__bf16)x.z; b[3] = (__bf16)x.w;
        b[4] = (__bf16)y.x; b[5] = (__bf16)y.y; b[6] = (__bf16)y.z; b[7] = (__bf16)y.w;
#pragma unroll
        for (int t = 0; t < 16; t++) {
            const __bf16* ap = wb + (size_t)(dbase + t * 16 + col) * K + kg * 8 + ks * 32;
            bf16x8 a = *(const bf16x8*)(ap);
            acc[t] = __builtin_amdgcn_mfma_f32_16x16x32_bf16(a, b, acc[t], 0, 0, 0);
        }
        bp += 32;
    }

    bool valid = col < nt;
    float* orow = out + (size_t)tok * D;
#pragma unroll
    for (int t = 0; t < 16; t++) {
        int d0 = dbase + t * 16 + kg * 4;
        float4 bs = *(const float4*)(bias + d0);
        if (valid) {
            float4 o;
            o.x = acc[t][0] + bs.x;
            o.y = acc[t][1] + bs.y;
            o.z = acc[t][2] + bs.z;
            o.w = acc[t][3] + bs.w;
            *(float4*)(orow + d0) = o;
        }
    }
}

// 1 wave per block. blocks [0,8192): cluster1; [8192,16384): cluster2.
// Within a cluster: slice = b >> 11 (d-quarter), tt = b & 2047 (token group).
__global__ __launch_bounds__(64) void k_gemm(
        const float* __restrict__ emb1,
        const float* __restrict__ emb2,
        const float* __restrict__ b1,
        const float* __restrict__ b2,
        float* __restrict__ out,
        const int* __restrict__ cnt,
        const unsigned* __restrict__ list1,
        const unsigned* __restrict__ list2,
        const __bf16* __restrict__ w1b,
        const __bf16* __restrict__ w2b) {
    int bid = blockIdx.x;
    int lane = threadIdx.x;
    bool c1 = bid < 8192;
    int b = c1 ? bid : bid - 8192;
    int slice = b >> 11, tt = b & 2047;
    int n = c1 ? cnt[1] : cnt[2];
    int base = tt * 16;
    if (base >= n) return;
    int dbase = slice * 256;

    if (c1)
        gemm_slice<D1, 8>(emb1, w1b, b1, out, list1, n, base, dbase, lane);
    else
        gemm_slice<D2, 2>(emb2, w2b, b2, out, list2, n, base, dbase, lane);
}

extern "C" void kernel_launch(void* const* d_in, const int* in_sizes, int n_in,
                              void* d_out, int out_size, void* d_ws, size_t ws_size,
                              hipStream_t stream) {
    const int*   ids  = (const int*)d_in[0];
    const float* emb0 = (const float*)d_in[1];
    const float* emb1 = (const float*)d_in[2];
    const float* emb2 = (const float*)d_in[3];
    const float* w1   = (const float*)d_in[4];
    const float* b1   = (const float*)d_in[5];
    const float* w2   = (const float*)d_in[6];
    const float* b2   = (const float*)d_in[7];
    float* out = (float*)d_out;

    int* cnt        = (int*)d_ws;
    unsigned* list0 = (unsigned*)(cnt + 64);   // 256 B offset
    unsigned* list1 = list0 + NTOK;
    unsigned* list2 = list1 + NTOK;
    __bf16* w1b     = (__bf16*)(list2 + NTOK);
    __bf16* w2b     = w1b + (size_t)D * D1;

    hipLaunchKernelGGL(k_init, dim3(1), dim3(64), 0, stream, cnt);
    // 128 token blocks + 1280 w-cast blocks
    hipLaunchKernelGGL(k_classify, dim3(NTOK / 256 + 1280), dim3(256), 0, stream,
                       ids, w1, w2, cnt, list0, list1, list2, w1b, w2b);
    hipLaunchKernelGGL(k_copy0, dim3(2048), dim3(256), 0, stream,
                       emb0, out, cnt, list0);
    hipLaunchKernelGGL(k_gemm, dim3(16384), dim3(64), 0, stream,
                       emb1, emb2, b1, b2, out, cnt, list1, list2, w1b, w2b);
}

// Round 6
// 95.729 us; speedup vs baseline: 1.2844x; 1.2844x over previous
//
#include <hip/hip_runtime.h>

#define CUT0 20000
#define CUT1 60000
#define D    1024
#define D1   256
#define D2   64
#define NTOK 32768

typedef __bf16  bf16x4 __attribute__((ext_vector_type(4)));
typedef __bf16  bf16x8 __attribute__((ext_vector_type(8)));
typedef float   f32x4  __attribute__((ext_vector_type(4)));

// ws layout:
//   int      cnt[64]
//   unsigned list0/1/2[NTOK]            packed (tok<<17)|local_idx
//   __bf16   w1b[D*D1], w2b[D*D2]       ([d][k] layout, MFMA A-operand rows)
//   __bf16   E1c[NTOK*D1], E2c[NTOK*D2] compact gathered bf16 E (B-operand rows)

__global__ void k_init(int* cnt) {
    if (threadIdx.x < 3) cnt[threadIdx.x] = 0;
}

__global__ __launch_bounds__(256) void k_classify(
        const int* __restrict__ ids,
        const float* __restrict__ w1,
        const float* __restrict__ w2,
        int* cnt, unsigned* list0, unsigned* list1, unsigned* list2,
        __bf16* __restrict__ w1b, __bf16* __restrict__ w2b) {
    int bid = blockIdx.x, tid = threadIdx.x;
    if (bid < NTOK / 256) {
        unsigned t = bid * 256 + tid;
        int id = ids[t];
        int lane = tid & 63;
        unsigned long long lanebit = 1ull << lane;
        int c = (id < CUT0) ? 0 : (id < CUT1 ? 1 : 2);
        {
            unsigned long long m = __ballot(c == 0);
            if (m) {
                int base = 0;
                if (lane == 0) base = atomicAdd(cnt + 0, __popcll(m));
                base = __shfl(base, 0);
                if (c == 0) list0[base + __popcll(m & (lanebit - 1))] = (t << 17) | (unsigned)id;
            }
        }
        {
            unsigned long long m = __ballot(c == 1);
            if (m) {
                int base = 0;
                if (lane == 0) base = atomicAdd(cnt + 1, __popcll(m));
                base = __shfl(base, 0);
                if (c == 1) list1[base + __popcll(m & (lanebit - 1))] = (t << 17) | (unsigned)(id - CUT0);
            }
        }
        {
            unsigned long long m = __ballot(c == 2);
            if (m) {
                int base = 0;
                if (lane == 0) base = atomicAdd(cnt + 2, __popcll(m));
                base = __shfl(base, 0);
                if (c == 2) list2[base + __popcll(m & (lanebit - 1))] = (t << 17) | (unsigned)(id - CUT1);
            }
        }
    } else {
        int i = (bid - NTOK / 256) * 256 + tid;
        if (i < D1 * D) {
            w1b[i] = (__bf16)w1[i];
        } else {
            int j = i - D1 * D;
            w2b[j] = (__bf16)w2[j];
        }
    }
}

// blocks [0,1536): c0 row copy; [1536,3072): E1 gather; [3072,4096): E2 gather
__global__ __launch_bounds__(256) void k_stage(
        const float* __restrict__ emb0,
        const float* __restrict__ emb1,
        const float* __restrict__ emb2,
        float* __restrict__ out,
        const int* __restrict__ cnt,
        const unsigned* __restrict__ list0,
        const unsigned* __restrict__ list1,
        const unsigned* __restrict__ list2,
        __bf16* __restrict__ E1, __bf16* __restrict__ E2, int staged) {
    int bid = blockIdx.x, tid = threadIdx.x;
    if (bid < 1536) {
        int n0 = cnt[0];
        for (int r = bid; r < n0; r += 1536) {
            unsigned p = list0[r];
            const float4* src = (const float4*)(emb0 + (size_t)(p & 0x1FFFFu) * D);
            float4* dst = (float4*)(out + (size_t)(p >> 17) * D);
            dst[tid] = src[tid];
        }
    } else if (bid < 3072) {
        if (!staged) return;
        int n1 = cnt[1];
        int rr = tid >> 6, lane = tid & 63;        // 4 rows / iter
        for (int r = (bid - 1536) * 4 + rr; r < n1; r += 1536 * 4) {
            unsigned lidx = list1[r] & 0x1FFFFu;
            float4 x = *(const float4*)(emb1 + (size_t)lidx * D1 + lane * 4);
            bf16x4 v = { (__bf16)x.x, (__bf16)x.y, (__bf16)x.z, (__bf16)x.w };
            *(bf16x4*)(E1 + (size_t)r * D1 + lane * 4) = v;
        }
    } else {
        if (!staged) return;
        int n2 = cnt[2];
        int rr = tid >> 4, lane = tid & 15;        // 16 rows / iter
        for (int r = (bid - 3072) * 16 + rr; r < n2; r += 1024 * 16) {
            unsigned lidx = list2[r] & 0x1FFFFu;
            float4 x = *(const float4*)(emb2 + (size_t)lidx * D2 + lane * 4);
            bf16x4 v = { (__bf16)x.x, (__bf16)x.y, (__bf16)x.z, (__bf16)x.w };
            *(bf16x4*)(E2 + (size_t)r * D2 + lane * 4) = v;
        }
    }
}

// Wave tile: 32 tokens x 128 d.  A-frag = w rows (d), B-frag = E rows (tokens).
// A: lane holds d-row wdbase+t*16+(lane&15), k=(lane>>4)*8+j (+32 per ks)
// B: lane holds token col (lane&15) [two tiles], same k slots
// C/D: col=lane&15 (token), row=(lane>>4)*4+r (d) -> float4 store per lane
template<int K, bool STAGED>
__device__ __forceinline__ void gemm_tile(
        const void* __restrict__ Esrc,
        const __bf16* __restrict__ wb,
        const float* __restrict__ bias, float* __restrict__ out,
        const unsigned* __restrict__ list, int n, int base, int wdbase, int lane) {
    constexpr int KS = K / 32;
    int col = lane & 15, kg = lane >> 4;
    int ti0 = base + col, ti1 = ti0 + 16;
    int ci0 = ti0 < n ? ti0 : n - 1;
    int ci1 = ti1 < n ? ti1 : n - 1;
    unsigned p0 = list[ci0], p1 = list[ci1];

    f32x4 acc[8][2];
#pragma unroll
    for (int t = 0; t < 8; t++) {
        acc[t][0] = (f32x4){0.f, 0.f, 0.f, 0.f};
        acc[t][1] = (f32x4){0.f, 0.f, 0.f, 0.f};
    }

    const __bf16* e0b = nullptr; const __bf16* e1b = nullptr;
    const float*  e0f = nullptr; const float*  e1f = nullptr;
    if constexpr (STAGED) {
        e0b = (const __bf16*)Esrc + (size_t)ci0 * K + kg * 8;
        e1b = (const __bf16*)Esrc + (size_t)ci1 * K + kg * 8;
    } else {
        e0f = (const float*)Esrc + (size_t)(p0 & 0x1FFFFu) * K + kg * 8;
        e1f = (const float*)Esrc + (size_t)(p1 & 0x1FFFFu) * K + kg * 8;
    }

#pragma unroll
    for (int ks = 0; ks < KS; ks++) {
        bf16x8 b0, b1;
        if constexpr (STAGED) {
            b0 = *(const bf16x8*)(e0b + ks * 32);
            b1 = *(const bf16x8*)(e1b + ks * 32);
        } else {
            float4 x0 = *(const float4*)(e0f + ks * 32);
            float4 y0 = *(const float4*)(e0f + ks * 32 + 4);
            float4 x1 = *(const float4*)(e1f + ks * 32);
            float4 y1 = *(const float4*)(e1f + ks * 32 + 4);
            b0[0] = (__bf16)x0.x; b0[1] = (__bf16)x0.y; b0[2] = (__bf16)x0.z; b0[3] = (__bf16)x0.w;
            b0[4] = (__bf16)y0.x; b0[5] = (__bf16)y0.y; b0[6] = (__bf16)y0.z; b0[7] = (__bf16)y0.w;
            b1[0] = (__bf16)x1.x; b1[1] = (__bf16)x1.y; b1[2] = (__bf16)x1.z; b1[3] = (__bf16)x1.w;
            b1[4] = (__bf16)y1.x; b1[5] = (__bf16)y1.y; b1[6] = (__bf16)y1.z; b1[7] = (__bf16)y1.w;
        }
#pragma unroll
        for (int t = 0; t < 8; t++) {
            bf16x8 a = *(const bf16x8*)(wb + (size_t)(wdbase + t * 16 + col) * K + kg * 8 + ks * 32);
            acc[t][0] = __builtin_amdgcn_mfma_f32_16x16x32_bf16(a, b0, acc[t][0], 0, 0, 0);
            acc[t][1] = __builtin_amdgcn_mfma_f32_16x16x32_bf16(a, b1, acc[t][1], 0, 0, 0);
        }
    }

    bool v0 = ti0 < n, v1 = ti1 < n;
    float* o0 = out + (size_t)(p0 >> 17) * D;
    float* o1 = out + (size_t)(p1 >> 17) * D;
#pragma unroll
    for (int t = 0; t < 8; t++) {
        int d0 = wdbase + t * 16 + kg * 4;
        float4 bs = *(const float4*)(bias + d0);
        if (v0) {
            float4 o = { acc[t][0][0] + bs.x, acc[t][0][1] + bs.y,
                         acc[t][0][2] + bs.z, acc[t][0][3] + bs.w };
            *(float4*)(o0 + d0) = o;
        }
        if (v1) {
            float4 o = { acc[t][1][0] + bs.x, acc[t][1][1] + bs.y,
                         acc[t][1][2] + bs.z, acc[t][1][3] + bs.w };
            *(float4*)(o1 + d0) = o;
        }
    }
}

// 4 waves/block; block = 32 tokens x 512 d (2 blocks per token group).
// blocks [0,2048): cluster1; [2048,4096): cluster2.
template<bool STAGED>
__global__ __launch_bounds__(256) void k_gemm(
        const void* __restrict__ E1src, const void* __restrict__ E2src,
        const float* __restrict__ b1, const float* __restrict__ b2,
        float* __restrict__ out,
        const int* __restrict__ cnt,
        const unsigned* __restrict__ list1,
        const unsigned* __restrict__ list2,
        const __bf16* __restrict__ w1b,
        const __bf16* __restrict__ w2b) {
    int bid = blockIdx.x;
    int lane = threadIdx.x & 63, wv = threadIdx.x >> 6;
    bool c1 = bid < 2048;
    int b = c1 ? bid : bid - 2048;
    int group = b >> 1, s = b & 1;
    int n = c1 ? cnt[1] : cnt[2];
    int base = group * 32;
    if (base >= n) return;
    int wdbase = s * 512 + wv * 128;

    if (c1)
        gemm_tile<D1, STAGED>(E1src, w1b, b1, out, list1, n, base, wdbase, lane);
    else
        gemm_tile<D2, STAGED>(E2src, w2b, b2, out, list2, n, base, wdbase, lane);
}

extern "C" void kernel_launch(void* const* d_in, const int* in_sizes, int n_in,
                              void* d_out, int out_size, void* d_ws, size_t ws_size,
                              hipStream_t stream) {
    const int*   ids  = (const int*)d_in[0];
    const float* emb0 = (const float*)d_in[1];
    const float* emb1 = (const float*)d_in[2];
    const float* emb2 = (const float*)d_in[3];
    const float* w1   = (const float*)d_in[4];
    const float* b1   = (const float*)d_in[5];
    const float* w2   = (const float*)d_in[6];
    const float* b2   = (const float*)d_in[7];
    float* out = (float*)d_out;

    int* cnt        = (int*)d_ws;
    unsigned* list0 = (unsigned*)((char*)d_ws + 256);
    unsigned* list1 = list0 + NTOK;
    unsigned* list2 = list1 + NTOK;
    __bf16* w1b     = (__bf16*)(list2 + NTOK);
    __bf16* w2b     = w1b + (size_t)D * D1;
    __bf16* E1      = w2b + (size_t)D * D2;
    __bf16* E2      = E1 + (size_t)NTOK * D1;
    size_t need = 256 + (size_t)3 * NTOK * 4
                + (size_t)(D * D1 + D * D2) * 2
                + (size_t)NTOK * (D1 + D2) * 2;
    int staged = (ws_size >= need) ? 1 : 0;

    hipLaunchKernelGGL(k_init, dim3(1), dim3(64), 0, stream, cnt);
    hipLaunchKernelGGL(k_classify, dim3(NTOK / 256 + 1280), dim3(256), 0, stream,
                       ids, w1, w2, cnt, list0, list1, list2, w1b, w2b);
    hipLaunchKernelGGL(k_stage, dim3(4096), dim3(256), 0, stream,
                       emb0, emb1, emb2, out, cnt, list0, list1, list2, E1, E2, staged);
    if (staged)
        hipLaunchKernelGGL((k_gemm<true>), dim3(4096), dim3(256), 0, stream,
                           (const void*)E1, (const void*)E2, b1, b2, out, cnt,
                           list1, list2, w1b, w2b);
    else
        hipLaunchKernelGGL((k_gemm<false>), dim3(4096), dim3(256), 0, stream,
                           (const void*)emb1, (const void*)emb2, b1, b2, out, cnt,
                           list1, list2, w1b, w2b);
}

// Round 7
// 86.912 us; speedup vs baseline: 1.4147x; 1.1014x over previous
//
#include <hip/hip_runtime.h>

#define CUT0 20000
#define CUT1 60000
#define D    1024
#define D1   256
#define D2   64
#define NTOK 32768

typedef __bf16  bf16x4 __attribute__((ext_vector_type(4)));
typedef __bf16  bf16x8 __attribute__((ext_vector_type(8)));
typedef float   f32x4  __attribute__((ext_vector_type(4)));

// ws layout:
//   int      cnt[64]
//   unsigned list0/1/2[NTOK]         packed (tok<<17)|local_idx
//   __bf16   w1b[D*D1], w2b[D*D2]    ([d][k] layout, MFMA A-operand rows)

__global__ void k_init(int* cnt) {
    if (threadIdx.x < 3) cnt[threadIdx.x] = 0;
}

__global__ __launch_bounds__(256) void k_classify(
        const int* __restrict__ ids,
        const float* __restrict__ w1,
        const float* __restrict__ w2,
        int* cnt, unsigned* list0, unsigned* list1, unsigned* list2,
        __bf16* __restrict__ w1b, __bf16* __restrict__ w2b) {
    int bid = blockIdx.x, tid = threadIdx.x;
    if (bid < NTOK / 256) {
        unsigned t = bid * 256 + tid;
        int id = ids[t];
        int lane = tid & 63;
        unsigned long long lanebit = 1ull << lane;
        int c = (id < CUT0) ? 0 : (id < CUT1 ? 1 : 2);
        {
            unsigned long long m = __ballot(c == 0);
            if (m) {
                int base = 0;
                if (lane == 0) base = atomicAdd(cnt + 0, __popcll(m));
                base = __shfl(base, 0);
                if (c == 0) list0[base + __popcll(m & (lanebit - 1))] = (t << 17) | (unsigned)id;
            }
        }
        {
            unsigned long long m = __ballot(c == 1);
            if (m) {
                int base = 0;
                if (lane == 0) base = atomicAdd(cnt + 1, __popcll(m));
                base = __shfl(base, 0);
                if (c == 1) list1[base + __popcll(m & (lanebit - 1))] = (t << 17) | (unsigned)(id - CUT0);
            }
        }
        {
            unsigned long long m = __ballot(c == 2);
            if (m) {
                int base = 0;
                if (lane == 0) base = atomicAdd(cnt + 2, __popcll(m));
                base = __shfl(base, 0);
                if (c == 2) list2[base + __popcll(m & (lanebit - 1))] = (t << 17) | (unsigned)(id - CUT1);
            }
        }
    } else {
        int i = (bid - NTOK / 256) * 256 + tid;
        if (i < D1 * D) {
            w1b[i] = (__bf16)w1[i];
        } else {
            int j = i - D1 * D;
            w2b[j] = (__bf16)w2[j];
        }
    }
}

// Fused per-cluster GEMM with in-block gather->LDS.
// Block = 256 thr (4 waves) = 64 tokens x 512 d (s picks d-half).
// Wave tile: 64 tok x 128 d, acc[8][4]; A = w rows (L2-resident bf16),
// B = gathered E rows in LDS, XOR-swizzled on 16B chunks.
// A: lane holds d-row wdb+t*16+(lane&15), k=(lane>>4)*8+j (+32/ks)
// B: lane holds token col c*16+(lane&15), same k slots
// C/D: col=lane&15 (token), row=(lane>>4)*4+r (d) -> float4 store/lane
template<int K>
__device__ __forceinline__ void gemm_block(
        const float* __restrict__ emb, const __bf16* __restrict__ wb,
        const float* __restrict__ bias, float* __restrict__ out,
        const unsigned* __restrict__ list, int n, int base, int sd,
        int tid, __bf16* Es, unsigned* plist) {
    constexpr int KS  = K / 32;
    constexpr int SWZ = (K / 8 >= 16) ? 15 : 7;   // XOR mask on 16B-chunk idx

    if (tid < 64) {
        int li = base + tid;
        plist[tid] = list[li < n ? li : n - 1];
    }
    __syncthreads();

    // gather 64 rows x K floats -> bf16 LDS (swizzled). thread: row=tid>>2, quarter=tid&3
    {
        int r = tid >> 2, q = tid & 3;
        unsigned lidx = plist[r] & 0x1FFFFu;
        const float* src = emb + (size_t)lidx * K + q * (K / 4);
#pragma unroll
        for (int f = 0; f < K / 16; f++) {
            float4 x = *(const float4*)(src + f * 4);
            bf16x4 v = { (__bf16)x.x, (__bf16)x.y, (__bf16)x.z, (__bf16)x.w };
            int k = q * (K / 4) + f * 4;
            int chunk = (k >> 3) ^ (r & SWZ);
            *(bf16x4*)(Es + r * K + chunk * 8 + (k & 7)) = v;
        }
    }
    __syncthreads();

    int lane = tid & 63, wv = tid >> 6;
    int row16 = lane & 15, kg = lane >> 4;
    int wdb = sd + wv * 128;

    f32x4 acc[8][4];
#pragma unroll
    for (int t = 0; t < 8; t++)
#pragma unroll
        for (int c = 0; c < 4; c++) acc[t][c] = (f32x4){0.f, 0.f, 0.f, 0.f};

#pragma unroll
    for (int ks = 0; ks < KS; ks++) {
        bf16x8 b[4];
#pragma unroll
        for (int c = 0; c < 4; c++) {
            int r = c * 16 + row16;
            int chunk = (kg + ks * 4) ^ (r & SWZ);
            b[c] = *(const bf16x8*)(Es + r * K + chunk * 8);
        }
#pragma unroll
        for (int t = 0; t < 8; t++) {
            bf16x8 a = *(const bf16x8*)(wb + (size_t)(wdb + t * 16 + row16) * K + kg * 8 + ks * 32);
#pragma unroll
            for (int c = 0; c < 4; c++)
                acc[t][c] = __builtin_amdgcn_mfma_f32_16x16x32_bf16(a, b[c], acc[t][c], 0, 0, 0);
        }
    }

#pragma unroll
    for (int t = 0; t < 8; t++) {
        int d0 = wdb + t * 16 + kg * 4;
        float4 bs = *(const float4*)(bias + d0);
#pragma unroll
        for (int c = 0; c < 4; c++) {
            int ti = c * 16 + row16;
            if (base + ti < n) {
                unsigned p = plist[ti];
                float4 o = { acc[t][c][0] + bs.x, acc[t][c][1] + bs.y,
                             acc[t][c][2] + bs.z, acc[t][c][3] + bs.w };
                *(float4*)(out + (size_t)(p >> 17) * D + d0) = o;
            }
        }
    }
}

// grid roles: [0,1024) c1 (group=bid>>1, d-half=bid&1); [1024,2048) c2; [2048,2560) c0 copy
__global__ __launch_bounds__(256) void k_fused(
        const float* __restrict__ emb0,
        const float* __restrict__ emb1,
        const float* __restrict__ emb2,
        const float* __restrict__ b1,
        const float* __restrict__ b2,
        float* __restrict__ out,
        const int* __restrict__ cnt,
        const unsigned* __restrict__ list0,
        const unsigned* __restrict__ list1,
        const unsigned* __restrict__ list2,
        const __bf16* __restrict__ w1b,
        const __bf16* __restrict__ w2b) {
    __shared__ __bf16 Es[64 * 256];
    __shared__ unsigned plist[64];

    int bid = blockIdx.x, tid = threadIdx.x;
    if (bid < 1024) {
        int n = cnt[1];
        int base = (bid >> 1) * 64;
        if (base >= n) return;
        gemm_block<D1>(emb1, w1b, b1, out, list1, n, base, (bid & 1) * 512, tid, Es, plist);
    } else if (bid < 2048) {
        int n = cnt[2];
        int b = bid - 1024;
        int base = (b >> 1) * 64;
        if (base >= n) return;
        gemm_block<D2>(emb2, w2b, b2, out, list2, n, base, (b & 1) * 512, tid, Es, plist);
    } else {
        int n0 = cnt[0];
        for (int r = bid - 2048; r < n0; r += 512) {
            unsigned p = list0[r];
            const float4* src = (const float4*)(emb0 + (size_t)(p & 0x1FFFFu) * D);
            float4* dst = (float4*)(out + (size_t)(p >> 17) * D);
            dst[tid] = src[tid];
        }
    }
}

extern "C" void kernel_launch(void* const* d_in, const int* in_sizes, int n_in,
                              void* d_out, int out_size, void* d_ws, size_t ws_size,
                              hipStream_t stream) {
    const int*   ids  = (const int*)d_in[0];
    const float* emb0 = (const float*)d_in[1];
    const float* emb1 = (const float*)d_in[2];
    const float* emb2 = (const float*)d_in[3];
    const float* w1   = (const float*)d_in[4];
    const float* b1   = (const float*)d_in[5];
    const float* w2   = (const float*)d_in[6];
    const float* b2   = (const float*)d_in[7];
    float* out = (float*)d_out;

    int* cnt        = (int*)d_ws;
    unsigned* list0 = (unsigned*)((char*)d_ws + 256);
    unsigned* list1 = list0 + NTOK;
    unsigned* list2 = list1 + NTOK;
    __bf16* w1b     = (__bf16*)(list2 + NTOK);
    __bf16* w2b     = w1b + (size_t)D * D1;

    hipLaunchKernelGGL(k_init, dim3(1), dim3(64), 0, stream, cnt);
    hipLaunchKernelGGL(k_classify, dim3(NTOK / 256 + 1280), dim3(256), 0, stream,
                       ids, w1, w2, cnt, list0, list1, list2, w1b, w2b);
    hipLaunchKernelGGL(k_fused, dim3(2560), dim3(256), 0, stream,
                       emb0, emb1, emb2, b1, b2, out, cnt,
                       list0, list1, list2, w1b, w2b);
}

// Round 8
// 73.694 us; speedup vs baseline: 1.6685x; 1.1794x over previous
//
#include <hip/hip_runtime.h>

#define CUT0 20000
#define CUT1 60000
#define D    1024
#define D1   256
#define D2   64
#define NTOK 32768

typedef __bf16  bf16x4 __attribute__((ext_vector_type(4)));
typedef __bf16  bf16x8 __attribute__((ext_vector_type(8)));
typedef float   f32x4  __attribute__((ext_vector_type(4)));

// ws layout:
//   int      cnt[64]
//   unsigned list0/1/2[NTOK]         packed (tok<<17)|local_idx
//   __bf16   w1b[D*D1], w2b[D*D2]    ([d][k] layout, MFMA A-operand rows)

__global__ __launch_bounds__(256) void k_classify(
        const int* __restrict__ ids,
        const float* __restrict__ w1,
        const float* __restrict__ w2,
        int* cnt, unsigned* list0, unsigned* list1, unsigned* list2,
        __bf16* __restrict__ w1b, __bf16* __restrict__ w2b) {
    int bid = blockIdx.x, tid = threadIdx.x;
    if (bid < NTOK / 256) {
        unsigned t = bid * 256 + tid;
        int id = ids[t];
        int lane = tid & 63;
        unsigned long long lanebit = 1ull << lane;
        int c = (id < CUT0) ? 0 : (id < CUT1 ? 1 : 2);
        {
            unsigned long long m = __ballot(c == 0);
            if (m) {
                int base = 0;
                if (lane == 0) base = atomicAdd(cnt + 0, __popcll(m));
                base = __shfl(base, 0);
                if (c == 0) list0[base + __popcll(m & (lanebit - 1))] = (t << 17) | (unsigned)id;
            }
        }
        {
            unsigned long long m = __ballot(c == 1);
            if (m) {
                int base = 0;
                if (lane == 0) base = atomicAdd(cnt + 1, __popcll(m));
                base = __shfl(base, 0);
                if (c == 1) list1[base + __popcll(m & (lanebit - 1))] = (t << 17) | (unsigned)(id - CUT0);
            }
        }
        {
            unsigned long long m = __ballot(c == 2);
            if (m) {
                int base = 0;
                if (lane == 0) base = atomicAdd(cnt + 2, __popcll(m));
                base = __shfl(base, 0);
                if (c == 2) list2[base + __popcll(m & (lanebit - 1))] = (t << 17) | (unsigned)(id - CUT1);
            }
        }
    } else {
        int i = (bid - NTOK / 256) * 256 + tid;
        if (i < D1 * D) {
            w1b[i] = (__bf16)w1[i];
        } else {
            int j = i - D1 * D;
            w2b[j] = (__bf16)w2[j];
        }
    }
}

// Fused gather->LDS + MFMA gemm. Block = 512 thr (8 waves) = 64 tok x 512 d.
// Wave tile: 64 tok x 64 d, acc[4][4] (64 acc VGPRs).
// A: lane holds w d-row wdb+t*16+(lane&15), k=(lane>>4)*8+j (+32/ks)
// B: lane holds token col c*16+(lane&15), same k slots (LDS, XOR-swizzled)
// C/D: col=lane&15 (token), row=(lane>>4)*4+r (d) -> float4 store/lane
template<int K>
__device__ __forceinline__ void gemm_block(
        const float* __restrict__ emb, const __bf16* __restrict__ wb,
        const float* __restrict__ bias, float* __restrict__ out,
        const unsigned* __restrict__ list, int n, int base, int sd,
        int tid, __bf16* Es, unsigned* plist) {
    constexpr int KS  = K / 32;
    constexpr int SWZ = (K / 8 >= 16) ? 15 : 7;   // XOR mask on 16B-chunk idx

    if (tid < 64) {
        int li = base + tid;
        plist[tid] = list[li < n ? li : n - 1];
    }
    __syncthreads();

    // gather 64 rows x K floats -> bf16 LDS (swizzled). 8 threads/row.
    {
        int r = tid >> 3, q = tid & 7;
        unsigned lidx = plist[r] & 0x1FFFFu;
        const float* src = emb + (size_t)lidx * K + q * (K / 8);
#pragma unroll
        for (int f = 0; f < K / 32; f++) {
            float4 x = *(const float4*)(src + f * 4);
            bf16x4 v = { (__bf16)x.x, (__bf16)x.y, (__bf16)x.z, (__bf16)x.w };
            int k = q * (K / 8) + f * 4;
            int chunk = (k >> 3) ^ (r & SWZ);
            *(bf16x4*)(Es + r * K + chunk * 8 + (k & 7)) = v;
        }
    }
    __syncthreads();

    int lane = tid & 63, wv = tid >> 6;
    int row16 = lane & 15, kg = lane >> 4;
    int wdb = sd + wv * 64;

    f32x4 acc[4][4];
#pragma unroll
    for (int t = 0; t < 4; t++)
#pragma unroll
        for (int c = 0; c < 4; c++) acc[t][c] = (f32x4){0.f, 0.f, 0.f, 0.f};

#pragma unroll
    for (int ks = 0; ks < KS; ks++) {
        bf16x8 b[4];
#pragma unroll
        for (int c = 0; c < 4; c++) {
            int r = c * 16 + row16;
            int chunk = (kg + ks * 4) ^ (r & SWZ);
            b[c] = *(const bf16x8*)(Es + r * K + chunk * 8);
        }
#pragma unroll
        for (int t = 0; t < 4; t++) {
            bf16x8 a = *(const bf16x8*)(wb + (size_t)(wdb + t * 16 + row16) * K + kg * 8 + ks * 32);
#pragma unroll
            for (int c = 0; c < 4; c++)
                acc[t][c] = __builtin_amdgcn_mfma_f32_16x16x32_bf16(a, b[c], acc[t][c], 0, 0, 0);
        }
    }

#pragma unroll
    for (int t = 0; t < 4; t++) {
        int d0 = wdb + t * 16 + kg * 4;
        float4 bs = *(const float4*)(bias + d0);
#pragma unroll
        for (int c = 0; c < 4; c++) {
            int ti = c * 16 + row16;
            if (base + ti < n) {
                unsigned p = plist[ti];
                float4 o = { acc[t][c][0] + bs.x, acc[t][c][1] + bs.y,
                             acc[t][c][2] + bs.z, acc[t][c][3] + bs.w };
                *(float4*)(out + (size_t)(p >> 17) * D + d0) = o;
            }
        }
    }
}

// grid: [0,1024) c1 (group=bid>>1, d-half=bid&1); [1024,2048) c2; [2048,2304) c0 copy
__global__ __launch_bounds__(512, 4) void k_fused(
        const float* __restrict__ emb0,
        const float* __restrict__ emb1,
        const float* __restrict__ emb2,
        const float* __restrict__ b1,
        const float* __restrict__ b2,
        float* __restrict__ out,
        const int* __restrict__ cnt,
        const unsigned* __restrict__ list0,
        const unsigned* __restrict__ list1,
        const unsigned* __restrict__ list2,
        const __bf16* __restrict__ w1b,
        const __bf16* __restrict__ w2b) {
    __shared__ __bf16 Es[64 * 256];
    __shared__ unsigned plist[64];

    int bid = blockIdx.x, tid = threadIdx.x;
    if (bid < 1024) {
        int n = cnt[1];
        int base = (bid >> 1) * 64;
        if (base >= n) return;
        gemm_block<D1>(emb1, w1b, b1, out, list1, n, base, (bid & 1) * 512, tid, Es, plist);
    } else if (bid < 2048) {
        int n = cnt[2];
        int b = bid - 1024;
        int base = (b >> 1) * 64;
        if (base >= n) return;
        gemm_block<D2>(emb2, w2b, b2, out, list2, n, base, (b & 1) * 512, tid, Es, plist);
    } else {
        int n0 = cnt[0];
        int f = tid & 255;
        for (int r = (bid - 2048) * 2 + (tid >> 8); r < n0; r += 512) {
            unsigned p = list0[r];
            const float4* src = (const float4*)(emb0 + (size_t)(p & 0x1FFFFu) * D);
            float4* dst = (float4*)(out + (size_t)(p >> 17) * D);
            dst[f] = src[f];
        }
    }
}

extern "C" void kernel_launch(void* const* d_in, const int* in_sizes, int n_in,
                              void* d_out, int out_size, void* d_ws, size_t ws_size,
                              hipStream_t stream) {
    const int*   ids  = (const int*)d_in[0];
    const float* emb0 = (const float*)d_in[1];
    const float* emb1 = (const float*)d_in[2];
    const float* emb2 = (const float*)d_in[3];
    const float* w1   = (const float*)d_in[4];
    const float* b1   = (const float*)d_in[5];
    const float* w2   = (const float*)d_in[6];
    const float* b2   = (const float*)d_in[7];
    float* out = (float*)d_out;

    int* cnt        = (int*)d_ws;
    unsigned* list0 = (unsigned*)((char*)d_ws + 256);
    unsigned* list1 = list0 + NTOK;
    unsigned* list2 = list1 + NTOK;
    __bf16* w1b     = (__bf16*)(list2 + NTOK);
    __bf16* w2b     = w1b + (size_t)D * D1;

    hipMemsetAsync(cnt, 0, 3 * sizeof(int), stream);
    hipLaunchKernelGGL(k_classify, dim3(NTOK / 256 + 1280), dim3(256), 0, stream,
                       ids, w1, w2, cnt, list0, list1, list2, w1b, w2b);
    hipLaunchKernelGGL(k_fused, dim3(2304), dim3(512), 0, stream,
                       emb0, emb1, emb2, b1, b2, out, cnt,
                       list0, list1, list2, w1b, w2b);
}

// Round 9
// 72.427 us; speedup vs baseline: 1.6977x; 1.0175x over previous
//
#include <hip/hip_runtime.h>

#define CUT0 20000
#define CUT1 60000
#define D    1024
#define D1   256
#define D2   64
#define NTOK 32768

typedef __bf16  bf16x4 __attribute__((ext_vector_type(4)));
typedef __bf16  bf16x8 __attribute__((ext_vector_type(8)));
typedef float   f32x4  __attribute__((ext_vector_type(4)));

// ws layout:
//   int      cnt[64]
//   unsigned list0/1/2[NTOK]         packed (tok<<17)|local_idx
//   __bf16   w1b[D*D1], w2b[D*D2]    ([d][k] layout, MFMA A-operand rows)

__global__ __launch_bounds__(256) void k_classify(
        const int* __restrict__ ids,
        const float* __restrict__ w1,
        const float* __restrict__ w2,
        int* cnt, unsigned* list0, unsigned* list1, unsigned* list2,
        __bf16* __restrict__ w1b, __bf16* __restrict__ w2b) {
    int bid = blockIdx.x, tid = threadIdx.x;
    if (bid < NTOK / 256) {
        unsigned t = bid * 256 + tid;
        int id = ids[t];
        int lane = tid & 63;
        unsigned long long lanebit = 1ull << lane;
        int c = (id < CUT0) ? 0 : (id < CUT1 ? 1 : 2);
        {
            unsigned long long m = __ballot(c == 0);
            if (m) {
                int base = 0;
                if (lane == 0) base = atomicAdd(cnt + 0, __popcll(m));
                base = __shfl(base, 0);
                if (c == 0) list0[base + __popcll(m & (lanebit - 1))] = (t << 17) | (unsigned)id;
            }
        }
        {
            unsigned long long m = __ballot(c == 1);
            if (m) {
                int base = 0;
                if (lane == 0) base = atomicAdd(cnt + 1, __popcll(m));
                base = __shfl(base, 0);
                if (c == 1) list1[base + __popcll(m & (lanebit - 1))] = (t << 17) | (unsigned)(id - CUT0);
            }
        }
        {
            unsigned long long m = __ballot(c == 2);
            if (m) {
                int base = 0;
                if (lane == 0) base = atomicAdd(cnt + 2, __popcll(m));
                base = __shfl(base, 0);
                if (c == 2) list2[base + __popcll(m & (lanebit - 1))] = (t << 17) | (unsigned)(id - CUT1);
            }
        }
    } else {
        int i = (bid - NTOK / 256) * 256 + tid;
        if (i < D1 * D) {
            w1b[i] = (__bf16)w1[i];
        } else {
            int j = i - D1 * D;
            w2b[j] = (__bf16)w2[j];
        }
    }
}

// Fused gather->LDS + MFMA gemm. Block = 1024 thr (16 waves) = 64 tok x 512 d.
// Wave tile: 64 tok x 32 d, acc[2][4] (32 acc VGPRs, ~60 total -> 8 waves/SIMD).
// A: lane holds w d-row wdb+t*16+(lane&15), k=(lane>>4)*8+j (+32/ks)
// B: lane holds token col c*16+(lane&15), same k slots (LDS, XOR-swizzled)
// C/D: col=lane&15 (token), row=(lane>>4)*4+r (d) -> float4 store/lane
template<int K>
__device__ __forceinline__ void gemm_block(
        const float* __restrict__ emb, const __bf16* __restrict__ wb,
        const float* __restrict__ bias, float* __restrict__ out,
        const unsigned* __restrict__ list, int n, int base, int sd,
        int tid, __bf16* Es, unsigned* plist) {
    constexpr int KS  = K / 32;
    constexpr int SWZ = (K / 8 >= 16) ? 15 : 7;   // XOR mask on 16B-chunk idx

    if (tid < 64) {
        int li = base + tid;
        plist[tid] = list[li < n ? li : n - 1];
    }
    __syncthreads();

    // gather 64 rows x K floats -> bf16 LDS (swizzled). 16 threads/row.
    {
        int r = tid >> 4, q = tid & 15;
        unsigned lidx = plist[r] & 0x1FFFFu;
        const float* src = emb + (size_t)lidx * K + q * (K / 16);
#pragma unroll
        for (int f = 0; f < K / 64; f++) {
            float4 x = *(const float4*)(src + f * 4);
            bf16x4 v = { (__bf16)x.x, (__bf16)x.y, (__bf16)x.z, (__bf16)x.w };
            int k = q * (K / 16) + f * 4;
            int chunk = (k >> 3) ^ (r & SWZ);
            *(bf16x4*)(Es + r * K + chunk * 8 + (k & 7)) = v;
        }
    }
    __syncthreads();

    int lane = tid & 63, wv = tid >> 6;       // wv 0..15
    int row16 = lane & 15, kg = lane >> 4;
    int wdb = sd + wv * 32;

    f32x4 acc[2][4];
#pragma unroll
    for (int t = 0; t < 2; t++)
#pragma unroll
        for (int c = 0; c < 4; c++) acc[t][c] = (f32x4){0.f, 0.f, 0.f, 0.f};

#pragma unroll
    for (int ks = 0; ks < KS; ks++) {
        bf16x8 a[2];
#pragma unroll
        for (int t = 0; t < 2; t++)
            a[t] = *(const bf16x8*)(wb + (size_t)(wdb + t * 16 + row16) * K + kg * 8 + ks * 32);
#pragma unroll
        for (int c = 0; c < 4; c++) {
            int r = c * 16 + row16;
            int chunk = (kg + ks * 4) ^ (r & SWZ);
            bf16x8 b = *(const bf16x8*)(Es + r * K + chunk * 8);
#pragma unroll
            for (int t = 0; t < 2; t++)
                acc[t][c] = __builtin_amdgcn_mfma_f32_16x16x32_bf16(a[t], b, acc[t][c], 0, 0, 0);
        }
    }

#pragma unroll
    for (int t = 0; t < 2; t++) {
        int d0 = wdb + t * 16 + kg * 4;
        float4 bs = *(const float4*)(bias + d0);
#pragma unroll
        for (int c = 0; c < 4; c++) {
            int ti = c * 16 + row16;
            if (base + ti < n) {
                unsigned p = plist[ti];
                float4 o = { acc[t][c][0] + bs.x, acc[t][c][1] + bs.y,
                             acc[t][c][2] + bs.z, acc[t][c][3] + bs.w };
                *(float4*)(out + (size_t)(p >> 17) * D + d0) = o;
            }
        }
    }
}

// grid: [0,1024) c1 (group=bid>>1, d-half=bid&1); [1024,2048) c2; [2048,2304) c0 copy
__global__ __launch_bounds__(1024, 8) void k_fused(
        const float* __restrict__ emb0,
        const float* __restrict__ emb1,
        const float* __restrict__ emb2,
        const float* __restrict__ b1,
        const float* __restrict__ b2,
        float* __restrict__ out,
        const int* __restrict__ cnt,
        const unsigned* __restrict__ list0,
        const unsigned* __restrict__ list1,
        const unsigned* __restrict__ list2,
        const __bf16* __restrict__ w1b,
        const __bf16* __restrict__ w2b) {
    __shared__ __bf16 Es[64 * 256];
    __shared__ unsigned plist[64];

    int bid = blockIdx.x, tid = threadIdx.x;
    if (bid < 1024) {
        int n = cnt[1];
        int base = (bid >> 1) * 64;
        if (base >= n) return;
        gemm_block<D1>(emb1, w1b, b1, out, list1, n, base, (bid & 1) * 512, tid, Es, plist);
    } else if (bid < 2048) {
        int n = cnt[2];
        int b = bid - 1024;
        int base = (b >> 1) * 64;
        if (base >= n) return;
        gemm_block<D2>(emb2, w2b, b2, out, list2, n, base, (b & 1) * 512, tid, Es, plist);
    } else {
        int n0 = cnt[0];
        int f = tid & 255;
        for (int r = (bid - 2048) * 4 + (tid >> 8); r < n0; r += 1024) {
            unsigned p = list0[r];
            const float4* src = (const float4*)(emb0 + (size_t)(p & 0x1FFFFu) * D);
            float4* dst = (float4*)(out + (size_t)(p >> 17) * D);
            dst[f] = src[f];
        }
    }
}

extern "C" void kernel_launch(void* const* d_in, const int* in_sizes, int n_in,
                              void* d_out, int out_size, void* d_ws, size_t ws_size,
                              hipStream_t stream) {
    const int*   ids  = (const int*)d_in[0];
    const float* emb0 = (const float*)d_in[1];
    const float* emb1 = (const float*)d_in[2];
    const float* emb2 = (const float*)d_in[3];
    const float* w1   = (const float*)d_in[4];
    const float* b1   = (const float*)d_in[5];
    const float* w2   = (const float*)d_in[6];
    const float* b2   = (const float*)d_in[7];
    float* out = (float*)d_out;

    int* cnt        = (int*)d_ws;
    unsigned* list0 = (unsigned*)((char*)d_ws + 256);
    unsigned* list1 = list0 + NTOK;
    unsigned* list2 = list1 + NTOK;
    __bf16* w1b     = (__bf16*)(list2 + NTOK);
    __bf16* w2b     = w1b + (size_t)D * D1;

    hipMemsetAsync(cnt, 0, 3 * sizeof(int), stream);
    hipLaunchKernelGGL(k_classify, dim3(NTOK / 256 + 1280), dim3(256), 0, stream,
                       ids, w1, w2, cnt, list0, list1, list2, w1b, w2b);
    hipLaunchKernelGGL(k_fused, dim3(2304), dim3(1024), 0, stream,
                       emb0, emb1, emb2, b1, b2, out, cnt,
                       list0, list1, list2, w1b, w2b);
}